// Round 3
// baseline (246.325 us; speedup 1.0000x reference)
//
#include <hip/hip_runtime.h>
#include <hip/hip_bf16.h>
#include <stdint.h>

#define N_PTS 8192
#define M_EDGES 131072
#define CIN 512
#define QKV_COLS 1536

typedef __bf16 bf16x8 __attribute__((ext_vector_type(8)));
typedef float f32x4 __attribute__((ext_vector_type(4)));
typedef float f32x8 __attribute__((ext_vector_type(8)));

#define GAS __attribute__((address_space(1)))
#define LAS __attribute__((address_space(3)))

__device__ __forceinline__ void gload_lds16(const void* g, void* l) {
  __builtin_amdgcn_global_load_lds((const GAS void*)g, (LAS void*)l, 16, 0, 0);
}

// ---------------- cast x_F -> bf16 A ----------------
__global__ void cast_a(const float* __restrict__ x, __bf16* __restrict__ a) {
  int i = blockIdx.x * blockDim.x + threadIdx.x;
  int base = i * 4;
  if (base < N_PTS * CIN) {
    float4 v = *(const float4*)(x + base);
    a[base + 0] = (__bf16)v.x;
    a[base + 1] = (__bf16)v.y;
    a[base + 2] = (__bf16)v.z;
    a[base + 3] = (__bf16)v.w;
  }
}

// ---------------- transpose+cast W (512x1536) -> BT (1536x512) bf16 ----------------
__global__ void cast_bt(const float* __restrict__ w, __bf16* __restrict__ bt) {
  __shared__ float tile[32][33];
  int bk = blockIdx.x, bn = blockIdx.y;
  int x = threadIdx.x & 31, y = threadIdx.x >> 5;
#pragma unroll
  for (int j = 0; j < 4; j++) {
    int r = y + j * 8;
    tile[r][x] = w[(size_t)(bk * 32 + r) * QKV_COLS + bn * 32 + x];
  }
  __syncthreads();
#pragma unroll
  for (int j = 0; j < 4; j++) {
    int r = y + j * 8;
    bt[(size_t)(bn * 32 + r) * CIN + bk * 32 + x] = (__bf16)tile[x][r];
  }
}

// ---------------- cast tables: qt/kt -> [h][ab][d] bf16 ----
__global__ void cast_tables(const float* __restrict__ qt, const float* __restrict__ kt,
                            __bf16* __restrict__ qtb, __bf16* __restrict__ ktb) {
  int i = blockIdx.x * 256 + threadIdx.x;
  if (i >= 3 * 48 * 512) return;
  // i = ab*512 + h*64 + d
  int d = i & 63, h = (i >> 6) & 7, ab = i >> 9;
  int po = (h * 144 + ab) * 64 + d;
  qtb[po] = (__bf16)qt[i];
  ktb[po] = (__bf16)kt[i];
}

// ---------------- bf16 MFMA GEMM: qkv = A * BT^T + bias -> qb/kb/vb bf16 ----------------
__global__ __launch_bounds__(256) void gemm_qkv(const __bf16* __restrict__ A,
                                                const __bf16* __restrict__ BT,
                                                const float* __restrict__ bias,
                                                __bf16* __restrict__ qb,
                                                __bf16* __restrict__ kb,
                                                __bf16* __restrict__ vb) {
  __shared__ __align__(16) char At[128 * 32 * 2];
  __shared__ __align__(16) char Bt[128 * 32 * 2];
  int tid = threadIdx.x;
  int w = tid >> 6, l = tid & 63;
  int bm = blockIdx.x, bn = blockIdx.y;
  int wm = w & 1, wn = w >> 1;
  f32x4 acc[4][4] = {};
  const char* Ab = (const char*)A;
  const char* Bb = (const char*)BT;

  for (int kt = 0; kt < 16; kt++) {
#pragma unroll
    for (int r = 0; r < 2; r++) {
      int flat = r * 4096 + w * 1024 + l * 16;
      int row = flat >> 6, colb = flat & 63;
      gload_lds16(Ab + ((size_t)(bm * 128 + row) * CIN + kt * 32) * 2 + colb,
                  At + r * 4096 + w * 1024);
      gload_lds16(Bb + ((size_t)(bn * 128 + row) * CIN + kt * 32) * 2 + colb,
                  Bt + r * 4096 + w * 1024);
    }
    __syncthreads();
    bf16x8 af[4], bfr[4];
    int lr = l & 15;
    int lk = (l >> 4) * 16;
#pragma unroll
    for (int mf = 0; mf < 4; mf++) af[mf] = *(const bf16x8*)(At + (wm * 64 + mf * 16 + lr) * 64 + lk);
#pragma unroll
    for (int nf = 0; nf < 4; nf++) bfr[nf] = *(const bf16x8*)(Bt + (wn * 64 + nf * 16 + lr) * 64 + lk);
#pragma unroll
    for (int mf = 0; mf < 4; mf++)
#pragma unroll
      for (int nf = 0; nf < 4; nf++)
        acc[mf][nf] = __builtin_amdgcn_mfma_f32_16x16x32_bf16(af[mf], bfr[nf], acc[mf][nf], 0, 0, 0);
    __syncthreads();
  }

  int lr = l & 15, lg = l >> 4;
#pragma unroll
  for (int mf = 0; mf < 4; mf++) {
#pragma unroll
    for (int nf = 0; nf < 4; nf++) {
      int gc = bn * 128 + wn * 64 + nf * 16 + lr;
      float b = bias[gc];
      int which = gc >> 9;
      int col = gc & 511;
      __bf16* dst = which == 0 ? qb : (which == 1 ? kb : vb);
      float scale = which == 0 ? 0.125f : 1.0f;
#pragma unroll
      for (int j = 0; j < 4; j++) {
        int gr = bm * 128 + wm * 64 + mf * 16 + lg * 4 + j;
        dst[(size_t)gr * 512 + col] = (__bf16)((acc[mf][nf][j] + b) * scale);
      }
    }
  }
}

// ---------------- table_dot: out[n][ab][h] (bf16) = src[n][h*64+:64] . tab[h][ab][:64] ----
__global__ __launch_bounds__(256) void table_dot(const __bf16* __restrict__ src,
                                                 const __bf16* __restrict__ tab,
                                                 __bf16* __restrict__ out) {
  __shared__ __align__(16) char As[128 * 128];   // [128 rows][64 bf16]
  __shared__ __align__(16) char Bs[144 * 128];   // [144 ab][64 bf16]
  int nt = blockIdx.x, h = blockIdx.y;
  int tid = threadIdx.x, w = tid >> 6, l = tid & 63;
  const char* sb = (const char*)src;
  const char* tb = (const char*)tab + (size_t)h * 144 * 128;
#pragma unroll
  for (int p = 0; p < 4; p++) {
    int flat = p * 4096 + w * 1024 + l * 16;
    int row = flat >> 7, colb = flat & 127;
    gload_lds16(sb + (size_t)(nt * 128 + row) * 1024 + h * 128 + colb, As + p * 4096 + w * 1024);
    gload_lds16(tb + flat, Bs + p * 4096 + w * 1024);
  }
  if (w < 2) {
    int flat = 16384 + w * 1024 + l * 16;
    gload_lds16(tb + flat, Bs + 16384 + w * 1024);
  }
  __syncthreads();

  f32x4 acc[2][9] = {};
  int lr = l & 15, lk = (l >> 4) * 16;
#pragma unroll
  for (int ks = 0; ks < 2; ks++) {
    bf16x8 af[2], bf[9];
#pragma unroll
    for (int mf = 0; mf < 2; mf++)
      af[mf] = *(const bf16x8*)(As + (w * 32 + mf * 16 + lr) * 128 + ks * 64 + lk);
#pragma unroll
    for (int nf = 0; nf < 9; nf++)
      bf[nf] = *(const bf16x8*)(Bs + (nf * 16 + lr) * 128 + ks * 64 + lk);
#pragma unroll
    for (int mf = 0; mf < 2; mf++)
#pragma unroll
      for (int nf = 0; nf < 9; nf++)
        acc[mf][nf] = __builtin_amdgcn_mfma_f32_16x16x32_bf16(af[mf], bf[nf], acc[mf][nf], 0, 0, 0);
  }

  int lg = l >> 4;
#pragma unroll
  for (int mf = 0; mf < 2; mf++)
#pragma unroll
    for (int nf = 0; nf < 9; nf++)
#pragma unroll
      for (int j = 0; j < 4; j++) {
        int n = nt * 128 + w * 32 + mf * 16 + lg * 4 + j;
        int ab = nf * 16 + lr;
        out[(size_t)n * 1152 + ab * 8 + h] = (__bf16)acc[mf][nf][j];
      }
}

// ---------------- edge setup ----------------
__global__ void edge_setup(const int* __restrict__ pairs, const float* __restrict__ xc,
                           int* __restrict__ qi_a, int* __restrict__ ki_a,
                           unsigned* __restrict__ bins, int* __restrict__ cnt) {
  int m = blockIdx.x * blockDim.x + threadIdx.x;
  if (m >= M_EDGES) return;
  int qi = pairs[m], ki = pairs[M_EDGES + m];
  unsigned pb = 0;
#pragma unroll
  for (int a = 0; a < 3; a++) {
    float rel = (xc[qi * 3 + a] - xc[ki * 3 + a]) / 0.05f + 24.0f;
    int b = (int)rel;
    b = b < 0 ? 0 : (b > 47 ? 47 : b);
    pb |= (unsigned)b << (6 * a);
  }
  qi_a[m] = qi;
  ki_a[m] = ki;
  bins[m] = pb;
  atomicAdd(&cnt[qi], 1);
}

// ---------------- scan: 256 threads, 32 counts each ----------------
__global__ __launch_bounds__(256) void scan_kernel(const int* __restrict__ cnt,
                                                   int* __restrict__ off,
                                                   int* __restrict__ cursor) {
  __shared__ int wsum[4];
  int tid = threadIdx.x, lane = tid & 63, w = tid >> 6;
  int local[32];
  int s = 0;
#pragma unroll
  for (int i = 0; i < 8; i++) {
    int4 v = ((const int4*)cnt)[tid * 8 + i];
    local[i * 4 + 0] = v.x; local[i * 4 + 1] = v.y;
    local[i * 4 + 2] = v.z; local[i * 4 + 3] = v.w;
    s += v.x + v.y + v.z + v.w;
  }
  int incl = s;
#pragma unroll
  for (int d = 1; d < 64; d <<= 1) {
    int t = __shfl_up(incl, d, 64);
    if (lane >= d) incl += t;
  }
  if (lane == 63) wsum[w] = incl;
  __syncthreads();
  int woff = 0;
#pragma unroll
  for (int j = 0; j < 4; j++) woff += (j < w) ? wsum[j] : 0;
  int run = woff + incl - s;
  int base = tid * 32;
#pragma unroll
  for (int i = 0; i < 32; i++) {
    off[base + i] = run;
    cursor[base + i] = run;
    run += local[i];
  }
  if (tid == 255) off[N_PTS] = run;
}

// ---------------- scatter edges into CSR (qi/ki/bins sorted) ----------------
__global__ void scatter_k(const int* __restrict__ qi_a, const int* __restrict__ ki_a,
                          const unsigned* __restrict__ bins, int* __restrict__ cursor,
                          int* __restrict__ qi_s, int* __restrict__ ki_s,
                          unsigned* __restrict__ bins_s) {
  int m = blockIdx.x * blockDim.x + threadIdx.x;
  if (m < M_EDGES) {
    int qi = qi_a[m];
    int pos = atomicAdd(&cursor[qi], 1);
    qi_s[pos] = qi;
    ki_s[pos] = ki_a[m];
    bins_s[pos] = bins[m];
  }
}

// ---------------- edge_bias: eb[e][h] = sum_a qdot[qi,a,bin]+kdot[ki,a,bin] ----------------
__global__ void edge_bias(const int* __restrict__ qi_s, const int* __restrict__ ki_s,
                          const unsigned* __restrict__ bins_s, const __bf16* __restrict__ qdot,
                          const __bf16* __restrict__ kdot, float* __restrict__ eb) {
  int t = blockIdx.x * 256 + threadIdx.x;
  int e = t >> 3, h = t & 7;
  if (e >= M_EDGES) return;
  int qi = qi_s[e], ki = ki_s[e];
  unsigned pb = bins_s[e];
  int a0 = ((int)(pb & 63)) * 8 + h;
  int a1 = (48 + (int)((pb >> 6) & 63)) * 8 + h;
  int a2 = (96 + (int)((pb >> 12) & 63)) * 8 + h;
  const __bf16* qd = qdot + qi * 1152;
  const __bf16* kd = kdot + ki * 1152;
  eb[t] = (float)qd[a0] + (float)qd[a1] + (float)qd[a2] +
          (float)kd[a0] + (float)kd[a1] + (float)kd[a2];
}

// ---------------- fused attention: persistent, one wave per (query, head) task ----
#define ATTN_BLOCKS 1024
__global__ __launch_bounds__(512) void attn_kernel(
    const __bf16* __restrict__ qb, const __bf16* __restrict__ kb,
    const __bf16* __restrict__ vb, const float* __restrict__ vt,
    const float* __restrict__ eb, const int* __restrict__ off,
    const int* __restrict__ ki_s, const unsigned* __restrict__ bins_s,
    float* __restrict__ out) {
  int tid = threadIdx.x;
  int w = tid >> 6, l = tid & 63;
  int es = l >> 3;  // edge slot 0..7
  int dg = l & 7;   // dim group: dims dg*8 .. dg*8+7
  int gwave = blockIdx.x * 8 + w;

  for (int task = gwave; task < N_PTS * 8; task += ATTN_BLOCKS * 8) {
    int n = task >> 3;
    int h = task & 7;
    int tcol = h * 64 + dg * 8;

    bf16x8 q8 = *(const bf16x8*)(qb + (n << 9) + tcol);
    float qv[8];
#pragma unroll
    for (int j = 0; j < 8; j++) qv[j] = (float)q8[j];

    float acc[8] = {0.f, 0.f, 0.f, 0.f, 0.f, 0.f, 0.f, 0.f};
    float den = 0.f;
    int e0 = off[n], e1 = off[n + 1];

    for (int base = e0; base < e1; base += 8) {
      int e = base + es;
      bool valid = e < e1;
      int ee = valid ? e : e0;
      int ki = ki_s[ee];
      unsigned pb = bins_s[ee];
      float ebv = eb[(ee << 3) + h];
      bf16x8 k8 = *(const bf16x8*)(kb + (ki << 9) + tcol);
      bf16x8 v8 = *(const bf16x8*)(vb + (ki << 9) + tcol);
      int b0 = pb & 63, b1 = (pb >> 6) & 63, b2 = (pb >> 12) & 63;
      f32x8 t0 = *(const f32x8*)(vt + (b0 << 9) + tcol);
      f32x8 t1 = *(const f32x8*)(vt + ((48 + b1) << 9) + tcol);
      f32x8 t2 = *(const f32x8*)(vt + ((96 + b2) << 9) + tcol);
      float p = 0.f;
#pragma unroll
      for (int j = 0; j < 8; j++) p += qv[j] * (float)k8[j];
      p += __shfl_xor(p, 1, 64);
      p += __shfl_xor(p, 2, 64);
      p += __shfl_xor(p, 4, 64);
      p += ebv;
      float ex = valid ? __expf(p) : 0.f;
      den += ex;
#pragma unroll
      for (int j = 0; j < 8; j++)
        acc[j] += ex * ((float)v8[j] + t0[j] + t1[j] + t2[j]);
    }

#pragma unroll
    for (int s = 8; s <= 32; s <<= 1) {
      den += __shfl_xor(den, s, 64);
#pragma unroll
      for (int j = 0; j < 8; j++) acc[j] += __shfl_xor(acc[j], s, 64);
    }

    if (es == 0) {
      float inv = (e1 > e0) ? 1.f / den : 0.f;
      float* op = out + (n << 9) + h * 64 + dg * 8;
      f32x4 o0 = {acc[0] * inv, acc[1] * inv, acc[2] * inv, acc[3] * inv};
      f32x4 o1 = {acc[4] * inv, acc[5] * inv, acc[6] * inv, acc[7] * inv};
      *(f32x4*)op = o0;
      *(f32x4*)(op + 4) = o1;
    }
  }
}

extern "C" void kernel_launch(void* const* d_in, const int* in_sizes, int n_in,
                              void* d_out, int out_size, void* d_ws, size_t ws_size,
                              hipStream_t stream) {
  const float* xF = (const float*)d_in[0];
  const float* xC = (const float*)d_in[1];
  const int* pairs = (const int*)d_in[2];
  const float* W = (const float*)d_in[3];
  const float* bias = (const float*)d_in[4];
  const float* qt = (const float*)d_in[5];
  const float* kt = (const float*)d_in[6];
  const float* vt = (const float*)d_in[7];
  float* out = (float*)d_out;

  char* ws = (char*)d_ws;
  size_t o = 0;
  auto alloc = [&](size_t bytes) {
    void* p = ws + o;
    o = (o + bytes + 255) & ~(size_t)255;
    return p;
  };
  __bf16* A = (__bf16*)alloc((size_t)N_PTS * CIN * 2);
  __bf16* BT = (__bf16*)alloc((size_t)QKV_COLS * CIN * 2);
  __bf16* qb = (__bf16*)alloc((size_t)N_PTS * 512 * 2);
  __bf16* kb = (__bf16*)alloc((size_t)N_PTS * 512 * 2);
  __bf16* vb = (__bf16*)alloc((size_t)N_PTS * 512 * 2);
  __bf16* qtb = (__bf16*)alloc((size_t)8 * 144 * 64 * 2);
  __bf16* ktb = (__bf16*)alloc((size_t)8 * 144 * 64 * 2);
  __bf16* qdot = (__bf16*)alloc((size_t)N_PTS * 1152 * 2);
  __bf16* kdot = (__bf16*)alloc((size_t)N_PTS * 1152 * 2);
  float* eb = (float*)alloc((size_t)M_EDGES * 8 * 4);
  int* qi_a = (int*)alloc(M_EDGES * 4);
  int* ki_a = (int*)alloc(M_EDGES * 4);
  unsigned* bins = (unsigned*)alloc(M_EDGES * 4);
  int* qi_s = (int*)alloc(M_EDGES * 4);
  int* ki_s = (int*)alloc(M_EDGES * 4);
  unsigned* bins_s = (unsigned*)alloc(M_EDGES * 4);
  int* cnt = (int*)alloc(N_PTS * 4);
  int* off = (int*)alloc((N_PTS + 1) * 4);
  int* cursor = (int*)alloc(N_PTS * 4);

  hipMemsetAsync(cnt, 0, N_PTS * 4, stream);

  cast_a<<<(N_PTS * CIN / 4 + 255) / 256, 256, 0, stream>>>(xF, A);
  cast_bt<<<dim3(CIN / 32, QKV_COLS / 32), 256, 0, stream>>>(W, BT);
  cast_tables<<<(3 * 48 * 512 + 255) / 256, 256, 0, stream>>>(qt, kt, qtb, ktb);
  gemm_qkv<<<dim3(N_PTS / 128, QKV_COLS / 128), 256, 0, stream>>>(A, BT, bias, qb, kb, vb);
  table_dot<<<dim3(N_PTS / 128, 8), 256, 0, stream>>>(qb, qtb, qdot);
  table_dot<<<dim3(N_PTS / 128, 8), 256, 0, stream>>>(kb, ktb, kdot);
  edge_setup<<<M_EDGES / 256, 256, 0, stream>>>(pairs, xC, qi_a, ki_a, bins, cnt);
  scan_kernel<<<1, 256, 0, stream>>>(cnt, off, cursor);
  scatter_k<<<M_EDGES / 256, 256, 0, stream>>>(qi_a, ki_a, bins, cursor, qi_s, ki_s, bins_s);
  edge_bias<<<(M_EDGES * 8) / 256, 256, 0, stream>>>(qi_s, ki_s, bins_s, qdot, kdot, eb);
  attn_kernel<<<ATTN_BLOCKS, 512, 0, stream>>>(qb, kb, vb, vt, eb, off, ki_s, bins_s, out);
}

// Round 4
// 169.547 us; speedup vs baseline: 1.4528x; 1.4528x over previous
//
#include <hip/hip_runtime.h>
#include <hip/hip_bf16.h>
#include <stdint.h>

#define N_PTS 8192
#define M_EDGES 131072
#define CIN 512
#define QKV_COLS 1536

typedef __bf16 bf16x8 __attribute__((ext_vector_type(8)));
typedef float f32x4 __attribute__((ext_vector_type(4)));

#define GAS __attribute__((address_space(1)))
#define LAS __attribute__((address_space(3)))

__device__ __forceinline__ void gload_lds16(const void* g, void* l) {
  __builtin_amdgcn_global_load_lds((const GAS void*)g, (LAS void*)l, 16, 0, 0);
}

// ---- prep: cast_a | cast_bt | cast_tables | edge_setup fused into one launch ----
__global__ __launch_bounds__(256) void prep_kernel(
    const float* __restrict__ xF, const float* __restrict__ W,
    const float* __restrict__ qt, const float* __restrict__ kt,
    const float* __restrict__ vt, const int* __restrict__ pairs,
    const float* __restrict__ xc,
    __bf16* __restrict__ A, __bf16* __restrict__ BT,
    __bf16* __restrict__ qtb, __bf16* __restrict__ ktb, __bf16* __restrict__ vtb,
    int* __restrict__ qi_a, unsigned* __restrict__ pack0, int* __restrict__ cnt) {
  __shared__ float tile[32][33];
  int b = blockIdx.x;
  int tid = threadIdx.x;
  if (b < 4096) {  // cast x_F -> bf16 A (exactly 4096*256*4 = N*CIN elems)
    int base = (b * 256 + tid) * 4;
    float4 v = *(const float4*)(xF + base);
    A[base + 0] = (__bf16)v.x;
    A[base + 1] = (__bf16)v.y;
    A[base + 2] = (__bf16)v.z;
    A[base + 3] = (__bf16)v.w;
  } else if (b < 4864) {  // transpose+cast W (512x1536) -> BT (1536x512)
    int blk = b - 4096;
    int bk = blk & 15, bn = blk >> 4;
    int x = tid & 31, y = tid >> 5;
#pragma unroll
    for (int j = 0; j < 4; j++) {
      int r = y + j * 8;
      tile[r][x] = W[(size_t)(bk * 32 + r) * QKV_COLS + bn * 32 + x];
    }
    __syncthreads();
#pragma unroll
    for (int j = 0; j < 4; j++) {
      int r = y + j * 8;
      BT[(size_t)(bn * 32 + r) * CIN + bk * 32 + x] = (__bf16)tile[x][r];
    }
  } else if (b < 5152) {  // cast tables (3*48*512 = 288*256 elems)
    int i = (b - 4864) * 256 + tid;
    int d = i & 63, h = (i >> 6) & 7, ab = i >> 9;
    int po = (h * 144 + ab) * 64 + d;
    qtb[po] = (__bf16)qt[i];
    ktb[po] = (__bf16)kt[i];
    vtb[i] = (__bf16)vt[i];
  } else {  // edge setup (512*256 = M edges)
    int m = (b - 5152) * 256 + tid;
    int qi = pairs[m], ki = pairs[M_EDGES + m];
    unsigned pb = 0;
#pragma unroll
    for (int a = 0; a < 3; a++) {
      float rel = (xc[qi * 3 + a] - xc[ki * 3 + a]) / 0.05f + 24.0f;
      int bb = (int)rel;
      bb = bb < 0 ? 0 : (bb > 47 ? 47 : bb);
      pb |= (unsigned)bb << (6 * a);
    }
    qi_a[m] = qi;
    pack0[m] = (unsigned)ki | (pb << 13);
    atomicAdd(&cnt[qi], 1);
  }
}

// ---- bf16 MFMA GEMM, BK=64, XOR-swizzled LDS: qkv = A*BT^T + bias -> qb/kb/vb ----
__global__ __launch_bounds__(256) void gemm_qkv(const __bf16* __restrict__ A,
                                                const __bf16* __restrict__ BT,
                                                const float* __restrict__ bias,
                                                __bf16* __restrict__ qb,
                                                __bf16* __restrict__ kb,
                                                __bf16* __restrict__ vb) {
  __shared__ __align__(16) char At[128 * 128];  // [128 rows][128B], swizzled
  __shared__ __align__(16) char Bt[128 * 128];
  int tid = threadIdx.x;
  int w = tid >> 6, l = tid & 63;
  int bm = blockIdx.x, bn = blockIdx.y;
  int wm = w & 1, wn = w >> 1;
  f32x4 acc[4][4] = {};
  const char* Ab = (const char*)A;
  const char* Bb = (const char*)BT;
  int lr = l & 15;
  int lk = (l >> 4) * 16;
  int xr = (lr & 7) << 4;  // read-side swizzle (row&7)<<4, rows ≡ lr mod 8

  for (int kt = 0; kt < 8; kt++) {
#pragma unroll
    for (int r = 0; r < 4; r++) {
      int flat = r * 4096 + tid * 16;
      int row = flat >> 7, colb = flat & 127;
      int gcolb = colb ^ ((row & 7) << 4);  // pre-swizzled global source
      gload_lds16(Ab + ((size_t)(bm * 128 + row) * CIN + kt * 64) * 2 + gcolb,
                  At + r * 4096 + w * 1024);
      gload_lds16(Bb + ((size_t)(bn * 128 + row) * CIN + kt * 64) * 2 + gcolb,
                  Bt + r * 4096 + w * 1024);
    }
    __syncthreads();
#pragma unroll
    for (int ks = 0; ks < 2; ks++) {
      bf16x8 af[4], bfr[4];
      int cs = (ks * 64 + lk) ^ xr;
#pragma unroll
      for (int mf = 0; mf < 4; mf++) af[mf] = *(const bf16x8*)(At + (wm * 64 + mf * 16 + lr) * 128 + cs);
#pragma unroll
      for (int nf = 0; nf < 4; nf++) bfr[nf] = *(const bf16x8*)(Bt + (wn * 64 + nf * 16 + lr) * 128 + cs);
#pragma unroll
      for (int mf = 0; mf < 4; mf++)
#pragma unroll
        for (int nf = 0; nf < 4; nf++)
          acc[mf][nf] = __builtin_amdgcn_mfma_f32_16x16x32_bf16(af[mf], bfr[nf], acc[mf][nf], 0, 0, 0);
    }
    __syncthreads();
  }

  int lg = l >> 4;
#pragma unroll
  for (int mf = 0; mf < 4; mf++) {
#pragma unroll
    for (int nf = 0; nf < 4; nf++) {
      int gc = bn * 128 + wn * 64 + nf * 16 + lr;
      float b = bias[gc];
      int which = gc >> 9;
      int col = gc & 511;
      __bf16* dst = which == 0 ? qb : (which == 1 ? kb : vb);
      float scale = which == 0 ? 0.125f : 1.0f;
#pragma unroll
      for (int j = 0; j < 4; j++) {
        int gr = bm * 128 + wm * 64 + mf * 16 + lg * 4 + j;
        dst[(size_t)gr * 512 + col] = (__bf16)((acc[mf][nf][j] + b) * scale);
      }
    }
  }
}

// ---- table_dot (q and k in one launch via z): out[n][ab*8+h] = src[n,h,:] . tab[h,ab,:] ----
__global__ __launch_bounds__(256) void table_dot(const __bf16* __restrict__ qb,
                                                 const __bf16* __restrict__ kb,
                                                 const __bf16* __restrict__ qtb,
                                                 const __bf16* __restrict__ ktb,
                                                 __bf16* __restrict__ qdot,
                                                 __bf16* __restrict__ kdot) {
  __shared__ __align__(16) char As[128 * 128];
  __shared__ __align__(16) char Bs[144 * 128];
  int nt = blockIdx.x, h = blockIdx.y, z = blockIdx.z;
  const __bf16* src = z ? kb : qb;
  const __bf16* tab = z ? ktb : qtb;
  __bf16* out = z ? kdot : qdot;
  int tid = threadIdx.x, w = tid >> 6, l = tid & 63;
  const char* sb = (const char*)src;
  const char* tb = (const char*)tab + (size_t)h * 144 * 128;
#pragma unroll
  for (int p = 0; p < 4; p++) {
    int flat = p * 4096 + tid * 16;
    int row = flat >> 7, colb = flat & 127;
    int gcolb = colb ^ ((row & 7) << 4);
    gload_lds16(sb + (size_t)(nt * 128 + row) * 1024 + h * 128 + gcolb, As + p * 4096 + w * 1024);
    gload_lds16(tb + row * 128 + gcolb, Bs + p * 4096 + w * 1024);
  }
  if (w < 2) {
    int flat = 16384 + w * 1024 + l * 16;
    int row = flat >> 7, colb = flat & 127;
    int gcolb = colb ^ ((row & 7) << 4);
    gload_lds16(tb + row * 128 + gcolb, Bs + 16384 + w * 1024);
  }
  __syncthreads();

  f32x4 acc[2][9] = {};
  int lr = l & 15, lk = (l >> 4) * 16;
  int xr = (lr & 7) << 4;
#pragma unroll
  for (int ks = 0; ks < 2; ks++) {
    bf16x8 af[2], bf[9];
    int cs = (ks * 64 + lk) ^ xr;
#pragma unroll
    for (int mf = 0; mf < 2; mf++)
      af[mf] = *(const bf16x8*)(As + (w * 32 + mf * 16 + lr) * 128 + cs);
#pragma unroll
    for (int nf = 0; nf < 9; nf++)
      bf[nf] = *(const bf16x8*)(Bs + (nf * 16 + lr) * 128 + cs);
#pragma unroll
    for (int mf = 0; mf < 2; mf++)
#pragma unroll
      for (int nf = 0; nf < 9; nf++)
        acc[mf][nf] = __builtin_amdgcn_mfma_f32_16x16x32_bf16(af[mf], bf[nf], acc[mf][nf], 0, 0, 0);
  }

  int lg = l >> 4;
#pragma unroll
  for (int mf = 0; mf < 2; mf++)
#pragma unroll
    for (int nf = 0; nf < 9; nf++)
#pragma unroll
      for (int j = 0; j < 4; j++) {
        int n = nt * 128 + w * 32 + mf * 16 + lg * 4 + j;
        int ab = nf * 16 + lr;
        out[(size_t)n * 1152 + ab * 8 + h] = (__bf16)acc[mf][nf][j];
      }
}

// ---- scan: 256 threads, 32 counts each ----
__global__ __launch_bounds__(256) void scan_kernel(const int* __restrict__ cnt,
                                                   int* __restrict__ off,
                                                   int* __restrict__ cursor) {
  __shared__ int wsum[4];
  int tid = threadIdx.x, lane = tid & 63, w = tid >> 6;
  int local[32];
  int s = 0;
#pragma unroll
  for (int i = 0; i < 8; i++) {
    int4 v = ((const int4*)cnt)[tid * 8 + i];
    local[i * 4 + 0] = v.x; local[i * 4 + 1] = v.y;
    local[i * 4 + 2] = v.z; local[i * 4 + 3] = v.w;
    s += v.x + v.y + v.z + v.w;
  }
  int incl = s;
#pragma unroll
  for (int d = 1; d < 64; d <<= 1) {
    int t = __shfl_up(incl, d, 64);
    if (lane >= d) incl += t;
  }
  if (lane == 63) wsum[w] = incl;
  __syncthreads();
  int woff = 0;
#pragma unroll
  for (int j = 0; j < 4; j++) woff += (j < w) ? wsum[j] : 0;
  int run = woff + incl - s;
  int base = tid * 32;
#pragma unroll
  for (int i = 0; i < 32; i++) {
    off[base + i] = run;
    cursor[base + i] = run;
    run += local[i];
  }
  if (tid == 255) off[N_PTS] = run;
}

// ---- scatter edges into CSR order ----
__global__ void scatter_k(const int* __restrict__ qi_a, const unsigned* __restrict__ pack0,
                          int* __restrict__ cursor, int* __restrict__ qi_s,
                          unsigned* __restrict__ epack) {
  int m = blockIdx.x * blockDim.x + threadIdx.x;
  if (m < M_EDGES) {
    int qi = qi_a[m];
    int pos = atomicAdd(&cursor[qi], 1);
    qi_s[pos] = qi;
    epack[pos] = pack0[m];
  }
}

// ---- edge_bias: eb[e][h] = sum_a qdot[qi,a,bin]+kdot[ki,a,bin] ----
__global__ void edge_bias(const int* __restrict__ qi_s, const unsigned* __restrict__ epack,
                          const __bf16* __restrict__ qdot, const __bf16* __restrict__ kdot,
                          float* __restrict__ eb) {
  int t = blockIdx.x * 256 + threadIdx.x;
  int e = t >> 3, h = t & 7;
  unsigned pk = epack[e];
  int ki = pk & 8191;
  unsigned pb = pk >> 13;
  int qi = qi_s[e];
  int a0 = ((int)(pb & 63)) * 8 + h;
  int a1 = (48 + (int)((pb >> 6) & 63)) * 8 + h;
  int a2 = (96 + (int)((pb >> 12) & 63)) * 8 + h;
  const __bf16* qd = qdot + qi * 1152;
  const __bf16* kd = kdot + ki * 1152;
  eb[t] = (float)qd[a0] + (float)qd[a1] + (float)qd[a2] +
          (float)kd[a0] + (float)kd[a1] + (float)kd[a2];
}

// ---- fused attention: block=query, wave=head, 16 edge slots in flight ----
__global__ __launch_bounds__(512) void attn_kernel(
    const __bf16* __restrict__ qb, const __bf16* __restrict__ kb,
    const __bf16* __restrict__ vb, const __bf16* __restrict__ vtb,
    const float* __restrict__ eb, const int* __restrict__ off,
    const unsigned* __restrict__ epack, float* __restrict__ out) {
  int n = blockIdx.x;
  int tid = threadIdx.x;
  int h = tid >> 6, l = tid & 63;
  int es = l >> 3, dg = l & 7;
  int tcol = h * 64 + dg * 8;

  bf16x8 q8 = *(const bf16x8*)(qb + (n << 9) + tcol);
  float qv[8];
#pragma unroll
  for (int j = 0; j < 8; j++) qv[j] = (float)q8[j];

  float acc[8] = {0.f, 0.f, 0.f, 0.f, 0.f, 0.f, 0.f, 0.f};
  float den = 0.f;
  int e0 = off[n], e1 = off[n + 1];

  for (int base = e0; base < e1; base += 16) {
    int eA = base + es;
    int eB = base + 8 + es;
    int cA = eA < e1 ? eA : e1 - 1;
    int cB = eB < e1 ? eB : e1 - 1;
    unsigned pA = epack[cA], pB = epack[cB];
    float ebA = eb[(cA << 3) + h], ebB = eb[(cB << 3) + h];
    int kiA = pA & 8191, kiB = pB & 8191;
    unsigned bA = pA >> 13, bB = pB >> 13;
    bf16x8 kA8 = *(const bf16x8*)(kb + (kiA << 9) + tcol);
    bf16x8 vA8 = *(const bf16x8*)(vb + (kiA << 9) + tcol);
    bf16x8 kB8 = *(const bf16x8*)(kb + (kiB << 9) + tcol);
    bf16x8 vB8 = *(const bf16x8*)(vb + (kiB << 9) + tcol);
    bf16x8 tA0 = *(const bf16x8*)(vtb + ((bA & 63u) << 9) + tcol);
    bf16x8 tA1 = *(const bf16x8*)(vtb + ((48 + ((bA >> 6) & 63u)) << 9) + tcol);
    bf16x8 tA2 = *(const bf16x8*)(vtb + ((96 + ((bA >> 12) & 63u)) << 9) + tcol);
    bf16x8 tB0 = *(const bf16x8*)(vtb + ((bB & 63u) << 9) + tcol);
    bf16x8 tB1 = *(const bf16x8*)(vtb + ((48 + ((bB >> 6) & 63u)) << 9) + tcol);
    bf16x8 tB2 = *(const bf16x8*)(vtb + ((96 + ((bB >> 12) & 63u)) << 9) + tcol);
    float p1 = 0.f, p2 = 0.f;
#pragma unroll
    for (int j = 0; j < 8; j++) {
      p1 += qv[j] * (float)kA8[j];
      p2 += qv[j] * (float)kB8[j];
    }
    p1 += __shfl_xor(p1, 1, 64);
    p2 += __shfl_xor(p2, 1, 64);
    p1 += __shfl_xor(p1, 2, 64);
    p2 += __shfl_xor(p2, 2, 64);
    p1 += __shfl_xor(p1, 4, 64);
    p2 += __shfl_xor(p2, 4, 64);
    p1 += ebA;
    p2 += ebB;
    float x1 = (eA < e1) ? __expf(p1) : 0.f;
    float x2 = (eB < e1) ? __expf(p2) : 0.f;
    den += x1 + x2;
#pragma unroll
    for (int j = 0; j < 8; j++)
      acc[j] += x1 * ((float)vA8[j] + (float)tA0[j] + (float)tA1[j] + (float)tA2[j]) +
                x2 * ((float)vB8[j] + (float)tB0[j] + (float)tB1[j] + (float)tB2[j]);
  }

#pragma unroll
  for (int s = 8; s <= 32; s <<= 1) {
    den += __shfl_xor(den, s, 64);
#pragma unroll
    for (int j = 0; j < 8; j++) acc[j] += __shfl_xor(acc[j], s, 64);
  }

  if (l < 8) {
    float inv = (e1 > e0) ? 1.f / den : 0.f;
    float* op = out + (n << 9) + h * 64 + l * 8;
    f32x4 o0 = {acc[0] * inv, acc[1] * inv, acc[2] * inv, acc[3] * inv};
    f32x4 o1 = {acc[4] * inv, acc[5] * inv, acc[6] * inv, acc[7] * inv};
    *(f32x4*)op = o0;
    *(f32x4*)(op + 4) = o1;
  }
}

extern "C" void kernel_launch(void* const* d_in, const int* in_sizes, int n_in,
                              void* d_out, int out_size, void* d_ws, size_t ws_size,
                              hipStream_t stream) {
  const float* xF = (const float*)d_in[0];
  const float* xC = (const float*)d_in[1];
  const int* pairs = (const int*)d_in[2];
  const float* W = (const float*)d_in[3];
  const float* bias = (const float*)d_in[4];
  const float* qt = (const float*)d_in[5];
  const float* kt = (const float*)d_in[6];
  const float* vt = (const float*)d_in[7];
  float* out = (float*)d_out;

  char* ws = (char*)d_ws;
  size_t o = 0;
  auto alloc = [&](size_t bytes) {
    void* p = ws + o;
    o = (o + bytes + 255) & ~(size_t)255;
    return p;
  };
  __bf16* A = (__bf16*)alloc((size_t)N_PTS * CIN * 2);
  __bf16* BT = (__bf16*)alloc((size_t)QKV_COLS * CIN * 2);
  __bf16* qb = (__bf16*)alloc((size_t)N_PTS * 512 * 2);
  __bf16* kb = (__bf16*)alloc((size_t)N_PTS * 512 * 2);
  __bf16* vb = (__bf16*)alloc((size_t)N_PTS * 512 * 2);
  __bf16* qtb = (__bf16*)alloc((size_t)8 * 144 * 64 * 2);
  __bf16* ktb = (__bf16*)alloc((size_t)8 * 144 * 64 * 2);
  __bf16* vtb = (__bf16*)alloc((size_t)144 * 512 * 2);
  __bf16* qdot = (__bf16*)alloc((size_t)N_PTS * 1152 * 2);
  __bf16* kdot = (__bf16*)alloc((size_t)N_PTS * 1152 * 2);
  float* eb = (float*)alloc((size_t)M_EDGES * 8 * 4);
  int* qi_a = (int*)alloc(M_EDGES * 4);
  unsigned* pack0 = (unsigned*)alloc(M_EDGES * 4);
  int* qi_s = (int*)alloc(M_EDGES * 4);
  unsigned* epack = (unsigned*)alloc(M_EDGES * 4);
  int* cnt = (int*)alloc(N_PTS * 4);
  int* off = (int*)alloc((N_PTS + 1) * 4);
  int* cursor = (int*)alloc(N_PTS * 4);

  hipMemsetAsync(cnt, 0, N_PTS * 4, stream);

  prep_kernel<<<5664, 256, 0, stream>>>(xF, W, qt, kt, vt, pairs, xC,
                                        A, BT, qtb, ktb, vtb, qi_a, pack0, cnt);
  scan_kernel<<<1, 256, 0, stream>>>(cnt, off, cursor);
  scatter_k<<<M_EDGES / 256, 256, 0, stream>>>(qi_a, pack0, cursor, qi_s, epack);
  gemm_qkv<<<dim3(N_PTS / 128, QKV_COLS / 128), 256, 0, stream>>>(A, BT, bias, qb, kb, vb);
  table_dot<<<dim3(N_PTS / 128, 8, 2), 256, 0, stream>>>(qb, kb, qtb, ktb, qdot, kdot);
  edge_bias<<<(M_EDGES * 8) / 256, 256, 0, stream>>>(qi_s, epack, qdot, kdot, eb);
  attn_kernel<<<N_PTS, 512, 0, stream>>>(qb, kb, vb, vtb, eb, off, epack, out);
}